// Round 7
// baseline (481.124 us; speedup 1.0000x reference)
//
#include <hip/hip_runtime.h>
#include <hip/hip_fp16.h>

#define TT 800
#define CC 80
#define BB 16
#define SS 128
#define INFV 1e9f
#define NLCB 113          // local chunks per band (904 steps / 8)
#define LAGCH 14          // chunk lag between bands (112 steps >= 98 + 8 + margin)
#define NGC 155           // 113 + 3*14
#define BANDH 200         // rows per band (4 bands x 200 = 800)
#define HALF_PER_BAND (113*50*32)     // 180800
#define HALF_PER_SLOT (4*113*50*32)   // 723200
#define SCALE 14.426950408889634f     // (1/gamma)*log2(e), gamma=0.1

// Bool masks may arrive as 1-byte numpy bools or int32 — detected at runtime.
__device__ inline bool mask_get(const void* p, int idx, int isInt) {
  if (isInt) return ((const int*)p)[idx] != 0;
  return ((const unsigned char*)p)[idx] != 0;
}

__device__ __forceinline__ float fexp2(float x) {
#if __has_builtin(__builtin_amdgcn_exp2f)
  return __builtin_amdgcn_exp2f(x);
#else
  return __expf(x * 0.6931471805599453f);
#endif
}
__device__ __forceinline__ float flog2(float x) {
#if __has_builtin(__builtin_amdgcn_logf)
  return __builtin_amdgcn_logf(x);
#else
  return __logf(x) * 1.4426950408889634f;
#endif
}
__device__ __forceinline__ float fmin3(float a, float b, float c) {
  return fminf(fminf(a, b), c);
}

// Single block: detect mask element width, compute d_loss into out[2].
__global__ __launch_bounds__(256) void detect_dloss_kernel(
    const float* __restrict__ d, const int* __restrict__ mel_len,
    const void* __restrict__ src_mask, const void* __restrict__ pred_mask,
    int* __restrict__ flags, float* __restrict__ out)
{
  __shared__ int nzs, nzp;
  __shared__ float lb[BB];
  int tid = threadIdx.x;
  if (tid == 0) { nzs = 0; nzp = 0; }
  __syncthreads();
  const unsigned char* sm = (const unsigned char*)src_mask;
  const unsigned char* pm = (const unsigned char*)pred_mask;
  int f = 0;
  for (int i = tid; i < BB * SS; i += 256) if ((i & 3) && sm[i]) f = 1;
  if (f) atomicOr(&nzs, 1);
  f = 0;
  for (int i = tid; i < BB * TT; i += 256) if ((i & 3) && pm[i]) f = 1;
  if (f) atomicOr(&nzp, 1);
  __syncthreads();
  int isIntS = nzs ? 0 : 1;
  if (tid == 0) { flags[0] = isIntS; flags[1] = nzp ? 0 : 1; }

  int b = tid >> 4, k = tid & 15;
  float sd = 0.f, so = 0.f;
  for (int s = k; s < SS; s += 16) {
    bool m = mask_get(src_mask, b * SS + s, isIntS);
    if (!m) { sd += d[b * SS + s]; so += 1.f; }
  }
  for (int off = 8; off; off >>= 1) {
    sd += __shfl_down(sd, off, 16);
    so += __shfl_down(so, off, 16);
  }
  if (k == 0) lb[b] = fabsf((float)mel_len[b] - sd) / so;
  __syncthreads();
  if (tid == 0) {
    float s = 0.f;
    for (int i = 0; i < BB; i++) s += lb[i];
    out[2] = s / (float)BB;
  }
}

// Cost matrix (pre-scaled by SCALE), chunk-transposed skew-2 layout:
// Dsk[slot][band][chunk][lane][step_in_chunk][4 rows] halfs, where for element
// (i,j): band=i/200, l=(i%200)>>2, rr=i&3, s=j+2l, chunk=s>>3, k=s&7.
__global__ __launch_bounds__(256) void cost_kernel(
    const float* __restrict__ mel, const float* __restrict__ post,
    const float* __restrict__ target, const void* __restrict__ pred_mask,
    const int* __restrict__ flags, __half* __restrict__ Dsk, int probBase)
{
  int slot = blockIdx.z;
  int prob = probBase + slot;
  int which = prob >> 4, b = prob & 15;
  const float* X = (which ? post : mel) + (size_t)b * TT * CC;
  const float* Y = target + (size_t)b * TT * CC;
  int i0 = blockIdx.y * 64, j0 = blockIdx.x * 64;
  int isInt = flags[1];

  __shared__ __attribute__((aligned(16))) float As[16][68];
  __shared__ __attribute__((aligned(16))) float Bs[16][68];

  int tid = threadIdx.x;
  int kk = tid & 15, r4 = tid >> 4;   // staging roles
  int tx = tid & 15, ty = tid >> 4;   // compute roles
  float acc[4][4] = {};

  for (int kc = 0; kc < CC; kc += 16) {
    __syncthreads();
#pragma unroll
    for (int q = 0; q < 4; q++) {
      int i = r4 + q * 16;
      int gia = i0 + i, gib = j0 + i;
      float xs = 0.f, ys = 0.f;
      if (gia < TT) {
        float v = X[(size_t)gia * CC + kc + kk];
        if (which == 0 && mask_get(pred_mask, b * TT + gia, isInt)) v = 0.f;
        xs = 1.f / (1.f + __expf(-v));
      }
      if (gib < TT) {
        float wv = Y[(size_t)gib * CC + kc + kk];
        ys = 1.f / (1.f + __expf(-wv));
      }
      As[kk][i] = xs;
      Bs[kk][i] = ys;
    }
    __syncthreads();
#pragma unroll
    for (int k = 0; k < 16; k++) {
      float4 a4 = *(const float4*)&As[k][ty * 4];
      float4 b4 = *(const float4*)&Bs[k][tx * 4];
      float am[4] = {a4.x, a4.y, a4.z, a4.w};
      float bn[4] = {b4.x, b4.y, b4.z, b4.w};
#pragma unroll
      for (int m = 0; m < 4; m++)
#pragma unroll
        for (int n = 0; n < 4; n++) {
          float df = am[m] - bn[n];
          acc[m][n] = fmaf(df, df, acc[m][n]);
        }
    }
  }

  // epilogue: store each thread's 4x4 quad (pre-scaled) to the skewed layout
  int i4 = i0 + ty * 4;
  if (i4 < TT) {
    int band = i4 / BANDH;
    int l = (i4 % BANDH) >> 2;
    __half* base = Dsk + (size_t)slot * HALF_PER_SLOT + (size_t)band * HALF_PER_BAND;
#pragma unroll
    for (int n = 0; n < 4; n++) {
      int j = j0 + tx * 4 + n;
      if (j < TT) {
        int s = j + 2 * l;
        int ch = s >> 3, k = s & 7;
        union { __half h[4]; uint2 u; } cv;
#pragma unroll
        for (int m = 0; m < 4; m++) cv.h[m] = __float2half(acc[m][n] * SCALE);
        *(uint2*)(base + ((size_t)(ch * 50 + l)) * 32 + k * 4) = cv.u;
      }
    }
  }
}

// Wave-pipelined soft-DTW (pre-scaled, anchored (m,s) form): 4 waves = 4 bands
// of 200 rows (lanes 0..49, 4 rows each), skew-2 so the cross-lane shfl is
// consumed one step after issue. The recursion chain carries only
// A=min3(m_prev,left,diag); m=d+A (≈16cy/cell). exp2/log2 hang off-chain:
// s = fma(s_prev, 2^(A-m_prev), 2^(A-left)+2^(A-diag)), r = m - log2(s) is
// finalized in parallel and consumed one step later. Mathematically exact
// (anchor choice is free); exponents all <= 0; s <= 9.
__global__ __launch_bounds__(256) void dtw_kernel(
    const __half* __restrict__ Dsk, float* __restrict__ out, int probBase)
{
  __shared__ float bnd[3][128];
  const int tid = threadIdx.x;
  const int w = tid >> 6, lane = tid & 63;
  const int slot = blockIdx.x;
  const int prob = probBase + slot;
  const int which = prob >> 4;
  const int lclamp = lane < 49 ? lane : 49;
  const __half* Db = Dsk + (size_t)slot * HALF_PER_SLOT + (size_t)w * HALF_PER_BAND;

  float cur0 = INFV, cur1 = INFV, cur2 = INFV, cur3 = INFV;
  float up_pipe = INFV, up_prev = INFV, rcarry = INFV, res = 0.f;
  float rbv[8], wrv[8];
#pragma unroll
  for (int k = 0; k < 8; k++) { rbv[k] = INFV; wrv[k] = INFV; }

  uint4 a0, a1, a2, a3, b0, b1, b2, b3;

#define PRE(P0, P1, P2, P3, LCN) do { if ((LCN) < NLCB) {                     \
    const uint4* p_ = (const uint4*)(Db + ((size_t)(LCN) * 50 + lclamp) * 32);\
    P0 = p_[0]; P1 = p_[1]; P2 = p_[2]; P3 = p_[3]; } } while (0)

#define RINGLOAD do { if (w) {                                                \
    const float4* rp_ = (const float4*)&bnd[w - 1][s0 & 127];                 \
    float4 ra_ = rp_[0], rc_ = rp_[1];                                        \
    rbv[0] = ra_.x; rbv[1] = ra_.y; rbv[2] = ra_.z; rbv[3] = ra_.w;           \
    rbv[4] = rc_.x; rbv[5] = rc_.y; rbv[6] = rc_.z; rbv[7] = rc_.w; } } while (0)

#define DO_STEP(K, LOU, HIU) do {                                             \
    const int s_ = s0 + (K);                                                  \
    float nxt_ = __shfl_up(cur3, 1, 64);                                      \
    unsigned lou_ = (LOU), hiu_ = (HIU);                                      \
    float2 f01 = __half22float2(*(const __half2*)&lou_);                      \
    float2 f23 = __half22float2(*(const __half2*)&hiu_);                      \
    float up_ = up_pipe, dg_ = up_prev;                                       \
    if (w == 0) { if (lane == 0) { up_ = INFV; dg_ = (s_ == 0) ? 0.0f : INFV; } } \
    else if (lane == 0) { up_ = rbv[(K)]; dg_ = ((K) == 0) ? rcarry : rbv[(K) == 0 ? 0 : (K) - 1]; } \
    float oc0 = cur0, oc1 = cur1, oc2 = cur2;                                 \
    /* cell0: prev = (up_, 1) */                                              \
    float A0 = fmin3(up_, cur0, dg_);                                         \
    float m0 = f01.x + A0;                                                    \
    float sv0 = fexp2(A0 - up_) + fexp2(A0 - cur0) + fexp2(A0 - dg_);         \
    /* cell1 */                                                               \
    float A1 = fmin3(m0, cur1, oc0);                                          \
    float m1 = f01.y + A1;                                                    \
    float sv1 = fmaf(sv0, fexp2(A1 - m0), fexp2(A1 - cur1) + fexp2(A1 - oc0));\
    /* cell2 */                                                               \
    float A2 = fmin3(m1, cur2, oc1);                                          \
    float m2 = f23.x + A2;                                                    \
    float sv2 = fmaf(sv1, fexp2(A2 - m1), fexp2(A2 - cur2) + fexp2(A2 - oc1));\
    /* cell3 */                                                               \
    float A3 = fmin3(m2, cur3, oc2);                                          \
    float m3 = f23.y + A3;                                                    \
    float sv3 = fmaf(sv2, fexp2(A3 - m2), fexp2(A3 - cur3) + fexp2(A3 - oc2));\
    /* finalize exact r (off the m-chain) */                                  \
    float r0 = m0 - flog2(sv0);                                               \
    float r1 = m1 - flog2(sv1);                                               \
    float r2 = m2 - flog2(sv2);                                               \
    float r3 = m3 - flog2(sv3);                                               \
    int j_ = s_ - 2 * lane;                                                   \
    bool act_ = (lane < 50) && ((unsigned)j_ < 800u);                         \
    cur0 = act_ ? r0 : INFV; cur1 = act_ ? r1 : INFV;                         \
    cur2 = act_ ? r2 : INFV; cur3 = act_ ? r3 : INFV;                         \
    wrv[(K)] = cur3;                                                          \
    if (s_ == 897) res = cur3;                                                \
    up_prev = up_pipe; up_pipe = nxt_;                                        \
  } while (0)

#define STEP8(Q0, Q1, Q2, Q3) do {                                            \
    DO_STEP(0, Q0.x, Q0.y); DO_STEP(1, Q0.z, Q0.w);                           \
    DO_STEP(2, Q1.x, Q1.y); DO_STEP(3, Q1.z, Q1.w);                           \
    DO_STEP(4, Q2.x, Q2.y); DO_STEP(5, Q2.z, Q2.w);                           \
    DO_STEP(6, Q3.x, Q3.y); DO_STEP(7, Q3.z, Q3.w); } while (0)

  // prologue: every wave loads its local chunk 0
  PRE(a0, a1, a2, a3, 0);
  __syncthreads();

  for (int G = 0; G < NGC; ++G) {
    const int lc = G - LAGCH * w;
    if (lc >= 0 && lc < NLCB) {
      const int s0 = lc << 3;
      if ((lc & 1) == 0) {
        PRE(b0, b1, b2, b3, lc + 1);
        RINGLOAD;
        STEP8(a0, a1, a2, a3);
      } else {
        PRE(a0, a1, a2, a3, lc + 1);
        RINGLOAD;
        STEP8(b0, b1, b2, b3);
      }
      if (w < 3 && lane == 49) {
#pragma unroll
        for (int k = 0; k < 8; k++) {
          int j = s0 + k - 98;
          if ((unsigned)j < 800u) bnd[w][j & 127] = wrv[k];
        }
      }
      rcarry = rbv[7];
    }
    __syncthreads();
  }

  // res is pre-scaled; unscale (1/SCALE) and apply 0.001/16 in one constant.
  if (w == 3 && lane == 49) atomicAdd(&out[which], res * 4.3321699e-6f);

#undef PRE
#undef RINGLOAD
#undef DO_STEP
#undef STEP8
}

extern "C" void kernel_launch(void* const* d_in, const int* in_sizes, int n_in,
                              void* d_out, int out_size, void* d_ws, size_t ws_size,
                              hipStream_t stream) {
  const float* d         = (const float*)d_in[0];
  const int*   mel_len   = (const int*)d_in[1];
  const float* mel       = (const float*)d_in[2];
  const float* post      = (const float*)d_in[3];
  const float* target    = (const float*)d_in[4];
  const void*  src_mask  = d_in[5];
  const void*  pred_mask = d_in[6];
  float* out = (float*)d_out;

  int* flags = (int*)d_ws;
  __half* Dsk = (__half*)((char*)d_ws + 256);
  size_t per = (size_t)HALF_PER_SLOT * sizeof(__half);  // 1.446 MB per problem
  int slots = 0;
  if (ws_size > 256) slots = (int)((ws_size - 256) / per);
  if (slots > 32) slots = 32;

  (void)hipMemsetAsync(d_out, 0, 3 * sizeof(float), stream);
  detect_dloss_kernel<<<1, 256, 0, stream>>>(d, mel_len, src_mask, pred_mask, flags, out);
  if (slots < 1) return;

  for (int base = 0; base < 32; base += slots) {
    int g = (32 - base < slots) ? (32 - base) : slots;
    cost_kernel<<<dim3(13, 13, g), 256, 0, stream>>>(mel, post, target, pred_mask,
                                                     flags, Dsk, base);
    dtw_kernel<<<g, 256, 0, stream>>>(Dsk, out, base);
  }
}

// Round 8
// 475.371 us; speedup vs baseline: 1.0121x; 1.0121x over previous
//
#include <hip/hip_runtime.h>
#include <hip/hip_fp16.h>

#define TT 800
#define CC 80
#define BB 16
#define SS 128
#define INFV 1e9f
#define NLCB 113          // local chunks per band (904 steps / 8)
#define LAGCH 14          // chunk lag between bands (112 steps >= 98 + 8 + margin)
#define NGC 155           // 113 + 3*14
#define BANDH 200         // rows per band (4 bands x 200 = 800)
#define HALF_PER_BAND (113*50*32)     // 180800
#define HALF_PER_SLOT (4*113*50*32)   // 723200
#define SCALE 14.426950408889634f     // (1/gamma)*log2(e), gamma=0.1

// Bool masks may arrive as 1-byte numpy bools or int32 — detected at runtime.
__device__ inline bool mask_get(const void* p, int idx, int isInt) {
  if (isInt) return ((const int*)p)[idx] != 0;
  return ((const unsigned char*)p)[idx] != 0;
}

__device__ __forceinline__ float fexp2(float x) {
#if __has_builtin(__builtin_amdgcn_exp2f)
  return __builtin_amdgcn_exp2f(x);
#else
  return __expf(x * 0.6931471805599453f);
#endif
}
__device__ __forceinline__ float flog2(float x) {
#if __has_builtin(__builtin_amdgcn_logf)
  return __builtin_amdgcn_logf(x);
#else
  return __logf(x) * 1.4426950408889634f;
#endif
}
__device__ __forceinline__ float fmin3(float a, float b, float c) {
  return fminf(fminf(a, b), c);
}

// Wave-wide shift-up-by-1 on the VALU pipe (no LDS): DPP compose.
// b1 = bcast31(x): lanes32-63 <- x[31] (others keep old=x)
// b2 = bcast15(old=b1, x): lanes16-31 <- x[15], 48-63 <- x[47]
// r  = row_shr:1(old=b2, x): lanes l%16!=0 <- x[l-1]; holes 16/32/48 <- b2 (correct);
//      lane0 <- junk (always overridden by caller).
__device__ __forceinline__ float shift_up1(float x) {
  int xi = __builtin_bit_cast(int, x);
  int b = __builtin_amdgcn_update_dpp(xi, xi, 0x143, 0xf, 0xf, false); // row_bcast31
  b = __builtin_amdgcn_update_dpp(b, xi, 0x142, 0xf, 0xf, false);      // row_bcast15
  b = __builtin_amdgcn_update_dpp(b, xi, 0x111, 0xf, 0xf, false);      // row_shr:1
  return __builtin_bit_cast(float, b);
}

// Single block: detect mask element width, compute d_loss into out[2].
__global__ __launch_bounds__(256) void detect_dloss_kernel(
    const float* __restrict__ d, const int* __restrict__ mel_len,
    const void* __restrict__ src_mask, const void* __restrict__ pred_mask,
    int* __restrict__ flags, float* __restrict__ out)
{
  __shared__ int nzs, nzp;
  __shared__ float lb[BB];
  int tid = threadIdx.x;
  if (tid == 0) { nzs = 0; nzp = 0; }
  __syncthreads();
  const unsigned char* sm = (const unsigned char*)src_mask;
  const unsigned char* pm = (const unsigned char*)pred_mask;
  int f = 0;
  for (int i = tid; i < BB * SS; i += 256) if ((i & 3) && sm[i]) f = 1;
  if (f) atomicOr(&nzs, 1);
  f = 0;
  for (int i = tid; i < BB * TT; i += 256) if ((i & 3) && pm[i]) f = 1;
  if (f) atomicOr(&nzp, 1);
  __syncthreads();
  int isIntS = nzs ? 0 : 1;
  if (tid == 0) { flags[0] = isIntS; flags[1] = nzp ? 0 : 1; }

  int b = tid >> 4, k = tid & 15;
  float sd = 0.f, so = 0.f;
  for (int s = k; s < SS; s += 16) {
    bool m = mask_get(src_mask, b * SS + s, isIntS);
    if (!m) { sd += d[b * SS + s]; so += 1.f; }
  }
  for (int off = 8; off; off >>= 1) {
    sd += __shfl_down(sd, off, 16);
    so += __shfl_down(so, off, 16);
  }
  if (k == 0) lb[b] = fabsf((float)mel_len[b] - sd) / so;
  __syncthreads();
  if (tid == 0) {
    float s = 0.f;
    for (int i = 0; i < BB; i++) s += lb[i];
    out[2] = s / (float)BB;
  }
}

// Cost matrix (pre-scaled by SCALE), chunk-transposed skew-2 layout:
// Dsk[slot][band][chunk][lane][step_in_chunk][4 rows] halfs, where for element
// (i,j): band=i/200, l=(i%200)>>2, rr=i&3, s=j+2l, chunk=s>>3, k=s&7.
__global__ __launch_bounds__(256) void cost_kernel(
    const float* __restrict__ mel, const float* __restrict__ post,
    const float* __restrict__ target, const void* __restrict__ pred_mask,
    const int* __restrict__ flags, __half* __restrict__ Dsk, int probBase)
{
  int slot = blockIdx.z;
  int prob = probBase + slot;
  int which = prob >> 4, b = prob & 15;
  const float* X = (which ? post : mel) + (size_t)b * TT * CC;
  const float* Y = target + (size_t)b * TT * CC;
  int i0 = blockIdx.y * 64, j0 = blockIdx.x * 64;
  int isInt = flags[1];

  __shared__ __attribute__((aligned(16))) float As[16][68];
  __shared__ __attribute__((aligned(16))) float Bs[16][68];

  int tid = threadIdx.x;
  int kk = tid & 15, r4 = tid >> 4;   // staging roles
  int tx = tid & 15, ty = tid >> 4;   // compute roles
  float acc[4][4] = {};

  for (int kc = 0; kc < CC; kc += 16) {
    __syncthreads();
#pragma unroll
    for (int q = 0; q < 4; q++) {
      int i = r4 + q * 16;
      int gia = i0 + i, gib = j0 + i;
      float xs = 0.f, ys = 0.f;
      if (gia < TT) {
        float v = X[(size_t)gia * CC + kc + kk];
        if (which == 0 && mask_get(pred_mask, b * TT + gia, isInt)) v = 0.f;
        xs = 1.f / (1.f + __expf(-v));
      }
      if (gib < TT) {
        float wv = Y[(size_t)gib * CC + kc + kk];
        ys = 1.f / (1.f + __expf(-wv));
      }
      As[kk][i] = xs;
      Bs[kk][i] = ys;
    }
    __syncthreads();
#pragma unroll
    for (int k = 0; k < 16; k++) {
      float4 a4 = *(const float4*)&As[k][ty * 4];
      float4 b4 = *(const float4*)&Bs[k][tx * 4];
      float am[4] = {a4.x, a4.y, a4.z, a4.w};
      float bn[4] = {b4.x, b4.y, b4.z, b4.w};
#pragma unroll
      for (int m = 0; m < 4; m++)
#pragma unroll
        for (int n = 0; n < 4; n++) {
          float df = am[m] - bn[n];
          acc[m][n] = fmaf(df, df, acc[m][n]);
        }
    }
  }

  // epilogue: store each thread's 4x4 quad (pre-scaled) to the skewed layout
  int i4 = i0 + ty * 4;
  if (i4 < TT) {
    int band = i4 / BANDH;
    int l = (i4 % BANDH) >> 2;
    __half* base = Dsk + (size_t)slot * HALF_PER_SLOT + (size_t)band * HALF_PER_BAND;
#pragma unroll
    for (int n = 0; n < 4; n++) {
      int j = j0 + tx * 4 + n;
      if (j < TT) {
        int s = j + 2 * l;
        int ch = s >> 3, k = s & 7;
        union { __half h[4]; uint2 u; } cv;
#pragma unroll
        for (int m = 0; m < 4; m++) cv.h[m] = __float2half(acc[m][n] * SCALE);
        *(uint2*)(base + ((size_t)(ch * 50 + l)) * 32 + k * 4) = cv.u;
      }
    }
  }
}

// Wave-pipelined soft-DTW (pre-scaled, anchored (m,s) form): 4 waves = 4 bands
// of 200 rows (lanes 0..49, 4 rows each), skew-2. The per-step cross-lane
// transfer is a 3-op DPP compose on the VALU pipe — zero DS ops per step.
__global__ __launch_bounds__(256) void dtw_kernel(
    const __half* __restrict__ Dsk, float* __restrict__ out, int probBase)
{
  __shared__ float bnd[3][128];
  const int tid = threadIdx.x;
  const int w = tid >> 6, lane = tid & 63;
  const int slot = blockIdx.x;
  const int prob = probBase + slot;
  const int which = prob >> 4;
  const int lclamp = lane < 49 ? lane : 49;
  const __half* Db = Dsk + (size_t)slot * HALF_PER_SLOT + (size_t)w * HALF_PER_BAND;

  float cur0 = INFV, cur1 = INFV, cur2 = INFV, cur3 = INFV;
  float up_pipe = INFV, up_prev = INFV, rcarry = INFV, res = 0.f;
  float rbv[8], wrv[8];
#pragma unroll
  for (int k = 0; k < 8; k++) { rbv[k] = INFV; wrv[k] = INFV; }

  uint4 a0, a1, a2, a3, b0, b1, b2, b3;

#define PRE(P0, P1, P2, P3, LCN) do { if ((LCN) < NLCB) {                     \
    const uint4* p_ = (const uint4*)(Db + ((size_t)(LCN) * 50 + lclamp) * 32);\
    P0 = p_[0]; P1 = p_[1]; P2 = p_[2]; P3 = p_[3]; } } while (0)

#define RINGLOAD do { if (w) {                                                \
    const float4* rp_ = (const float4*)&bnd[w - 1][s0 & 127];                 \
    float4 ra_ = rp_[0], rc_ = rp_[1];                                        \
    rbv[0] = ra_.x; rbv[1] = ra_.y; rbv[2] = ra_.z; rbv[3] = ra_.w;           \
    rbv[4] = rc_.x; rbv[5] = rc_.y; rbv[6] = rc_.z; rbv[7] = rc_.w; } } while (0)

#define DO_STEP(K, LOU, HIU) do {                                             \
    const int s_ = s0 + (K);                                                  \
    float nxt_ = shift_up1(cur3);                                             \
    unsigned lou_ = (LOU), hiu_ = (HIU);                                      \
    float2 f01 = __half22float2(*(const __half2*)&lou_);                      \
    float2 f23 = __half22float2(*(const __half2*)&hiu_);                      \
    float up_ = up_pipe, dg_ = up_prev;                                       \
    if (w == 0) { if (lane == 0) { up_ = INFV; dg_ = (s_ == 0) ? 0.0f : INFV; } } \
    else if (lane == 0) { up_ = rbv[(K)]; dg_ = ((K) == 0) ? rcarry : rbv[(K) == 0 ? 0 : (K) - 1]; } \
    float oc0 = cur0, oc1 = cur1, oc2 = cur2;                                 \
    /* cell0: prev = (up_, 1) */                                              \
    float A0 = fmin3(up_, cur0, dg_);                                         \
    float m0 = f01.x + A0;                                                    \
    float sv0 = fexp2(A0 - up_) + fexp2(A0 - cur0) + fexp2(A0 - dg_);         \
    /* cell1 */                                                               \
    float A1 = fmin3(m0, cur1, oc0);                                          \
    float m1 = f01.y + A1;                                                    \
    float sv1 = fmaf(sv0, fexp2(A1 - m0), fexp2(A1 - cur1) + fexp2(A1 - oc0));\
    /* cell2 */                                                               \
    float A2 = fmin3(m1, cur2, oc1);                                          \
    float m2 = f23.x + A2;                                                    \
    float sv2 = fmaf(sv1, fexp2(A2 - m1), fexp2(A2 - cur2) + fexp2(A2 - oc1));\
    /* cell3 */                                                               \
    float A3 = fmin3(m2, cur3, oc2);                                          \
    float m3 = f23.y + A3;                                                    \
    float sv3 = fmaf(sv2, fexp2(A3 - m2), fexp2(A3 - cur3) + fexp2(A3 - oc2));\
    /* finalize exact r (off the m-chain) */                                  \
    float r0 = m0 - flog2(sv0);                                               \
    float r1 = m1 - flog2(sv1);                                               \
    float r2 = m2 - flog2(sv2);                                               \
    float r3 = m3 - flog2(sv3);                                               \
    int j_ = s_ - 2 * lane;                                                   \
    bool act_ = (lane < 50) && ((unsigned)j_ < 800u);                         \
    cur0 = act_ ? r0 : INFV; cur1 = act_ ? r1 : INFV;                         \
    cur2 = act_ ? r2 : INFV; cur3 = act_ ? r3 : INFV;                         \
    wrv[(K)] = cur3;                                                          \
    if (s_ == 897) res = cur3;                                                \
    up_prev = up_pipe; up_pipe = nxt_;                                        \
  } while (0)

#define STEP8(Q0, Q1, Q2, Q3) do {                                            \
    DO_STEP(0, Q0.x, Q0.y); DO_STEP(1, Q0.z, Q0.w);                           \
    DO_STEP(2, Q1.x, Q1.y); DO_STEP(3, Q1.z, Q1.w);                           \
    DO_STEP(4, Q2.x, Q2.y); DO_STEP(5, Q2.z, Q2.w);                           \
    DO_STEP(6, Q3.x, Q3.y); DO_STEP(7, Q3.z, Q3.w); } while (0)

  // prologue: every wave loads its local chunk 0
  PRE(a0, a1, a2, a3, 0);
  __syncthreads();

  for (int G = 0; G < NGC; ++G) {
    const int lc = G - LAGCH * w;
    if (lc >= 0 && lc < NLCB) {
      const int s0 = lc << 3;
      if ((lc & 1) == 0) {
        PRE(b0, b1, b2, b3, lc + 1);
        RINGLOAD;
        STEP8(a0, a1, a2, a3);
      } else {
        PRE(a0, a1, a2, a3, lc + 1);
        RINGLOAD;
        STEP8(b0, b1, b2, b3);
      }
      if (w < 3 && lane == 49) {
#pragma unroll
        for (int k = 0; k < 8; k++) {
          int j = s0 + k - 98;
          if ((unsigned)j < 800u) bnd[w][j & 127] = wrv[k];
        }
      }
      rcarry = rbv[7];
    }
    __syncthreads();
  }

  // res is pre-scaled; unscale (1/SCALE) and apply 0.001/16 in one constant.
  if (w == 3 && lane == 49) atomicAdd(&out[which], res * 4.3321699e-6f);

#undef PRE
#undef RINGLOAD
#undef DO_STEP
#undef STEP8
}

extern "C" void kernel_launch(void* const* d_in, const int* in_sizes, int n_in,
                              void* d_out, int out_size, void* d_ws, size_t ws_size,
                              hipStream_t stream) {
  const float* d         = (const float*)d_in[0];
  const int*   mel_len   = (const int*)d_in[1];
  const float* mel       = (const float*)d_in[2];
  const float* post      = (const float*)d_in[3];
  const float* target    = (const float*)d_in[4];
  const void*  src_mask  = d_in[5];
  const void*  pred_mask = d_in[6];
  float* out = (float*)d_out;

  int* flags = (int*)d_ws;
  __half* Dsk = (__half*)((char*)d_ws + 256);
  size_t per = (size_t)HALF_PER_SLOT * sizeof(__half);  // 1.446 MB per problem
  int slots = 0;
  if (ws_size > 256) slots = (int)((ws_size - 256) / per);
  if (slots > 32) slots = 32;

  (void)hipMemsetAsync(d_out, 0, 3 * sizeof(float), stream);
  detect_dloss_kernel<<<1, 256, 0, stream>>>(d, mel_len, src_mask, pred_mask, flags, out);
  if (slots < 1) return;

  for (int base = 0; base < 32; base += slots) {
    int g = (32 - base < slots) ? (32 - base) : slots;
    cost_kernel<<<dim3(13, 13, g), 256, 0, stream>>>(mel, post, target, pred_mask,
                                                     flags, Dsk, base);
    dtw_kernel<<<g, 256, 0, stream>>>(Dsk, out, base);
  }
}